// Round 14
// baseline (515.255 us; speedup 1.0000x reference)
//
#include <hip/hip_runtime.h>

#define BB   16
#define SS   512
#define DD   1024
#define HH   16
#define DKK  64
#define DFFN 4096
#define LN_EPS 1e-6f
#define QSCALE 0.18033688011112042f   // 0.125 * log2(e)

typedef __attribute__((ext_vector_type(8))) __bf16 bf16x8;
typedef __attribute__((ext_vector_type(4))) float f32x4;
typedef __attribute__((ext_vector_type(8))) unsigned short ushort8;
typedef __attribute__((ext_vector_type(4))) unsigned short ushort4_t;

#define AS1 __attribute__((address_space(1)))
#define AS3 __attribute__((address_space(3)))

__device__ __forceinline__ unsigned short f2bf(float f) {
  unsigned int u = __float_as_uint(f);
  u += 0x7FFFu + ((u >> 16) & 1u);   // round-nearest-even
  return (unsigned short)(u >> 16);
}
__device__ __forceinline__ float bf2f(unsigned short u) {
  return __uint_as_float(((unsigned int)u) << 16);
}

// exact: 0.5x(1+tanh(t)) == x * sigmoid(2t)
__device__ __forceinline__ float gelu_f(float x) {
  float t = 0.7978845608028654f * (x + 0.044715f * x * x * x);
  return x / (1.0f + __expf(-2.0f * t));
}

__device__ __forceinline__ void sbar() {
  __builtin_amdgcn_sched_barrier(0);
  __builtin_amdgcn_s_barrier();
  __builtin_amdgcn_sched_barrier(0);
}
#define WAITVM(N)                                         \
  do {                                                    \
    __builtin_amdgcn_sched_barrier(0);                    \
    asm volatile("s_waitcnt vmcnt(" #N ")" ::: "memory"); \
    __builtin_amdgcn_sched_barrier(0);                    \
  } while (0)

// ---------------- LayerNorm: fp32 in -> bf16 out (strided out)
__global__ __launch_bounds__(256) void ln_kernel(const float* __restrict__ x,
                                                 const float* __restrict__ g,
                                                 const float* __restrict__ b,
                                                 unsigned short* __restrict__ out, int ldo) {
  const int row = blockIdx.x;
  const int tid = threadIdx.x;
  const float* xr = x + (size_t)row * DD;
  float4 v = *(const float4*)(xr + tid * 4);
  float s = v.x + v.y + v.z + v.w;
#pragma unroll
  for (int off = 1; off < 64; off <<= 1) s += __shfl_xor(s, off);
  __shared__ float red[8];
  const int wid = tid >> 6, l = tid & 63;
  if (l == 0) red[wid] = s;
  __syncthreads();
  const float mean = (red[0] + red[1] + red[2] + red[3]) * (1.0f / DD);
  float4 d;
  d.x = v.x - mean; d.y = v.y - mean; d.z = v.z - mean; d.w = v.w - mean;
  float ss = d.x * d.x + d.y * d.y + d.z * d.z + d.w * d.w;
#pragma unroll
  for (int off = 1; off < 64; off <<= 1) ss += __shfl_xor(ss, off);
  if (l == 0) red[4 + wid] = ss;
  __syncthreads();
  const float var = (red[4] + red[5] + red[6] + red[7]) * (1.0f / (DD - 1));
  const float scale = 1.0f / (sqrtf(var) + LN_EPS);
  float4 gv = *(const float4*)(g + tid * 4);
  float4 bv = *(const float4*)(b + tid * 4);
  ushort4_t o;
  o[0] = f2bf(gv.x * d.x * scale + bv.x);
  o[1] = f2bf(gv.y * d.y * scale + bv.y);
  o[2] = f2bf(gv.z * d.z * scale + bv.z);
  o[3] = f2bf(gv.w * d.w * scale + bv.w);
  *(ushort4_t*)(out + (size_t)row * ldo + tid * 4) = o;
}

// ---------------- ln1(x) AND bf16(time) into xt2[row][0..1024 | 1024..2048]
__global__ __launch_bounds__(256) void ln_time(const float* __restrict__ x,
                                               const float* __restrict__ g,
                                               const float* __restrict__ b,
                                               const float* __restrict__ timep,
                                               unsigned short* __restrict__ out) {
  const int row = blockIdx.x;
  const int tid = threadIdx.x;
  const float* xr = x + (size_t)row * DD;
  float4 v = *(const float4*)(xr + tid * 4);
  float s = v.x + v.y + v.z + v.w;
#pragma unroll
  for (int off = 1; off < 64; off <<= 1) s += __shfl_xor(s, off);
  __shared__ float red[8];
  const int wid = tid >> 6, l = tid & 63;
  if (l == 0) red[wid] = s;
  __syncthreads();
  const float mean = (red[0] + red[1] + red[2] + red[3]) * (1.0f / DD);
  float4 d;
  d.x = v.x - mean; d.y = v.y - mean; d.z = v.z - mean; d.w = v.w - mean;
  float ss = d.x * d.x + d.y * d.y + d.z * d.z + d.w * d.w;
#pragma unroll
  for (int off = 1; off < 64; off <<= 1) ss += __shfl_xor(ss, off);
  if (l == 0) red[4 + wid] = ss;
  __syncthreads();
  const float var = (red[4] + red[5] + red[6] + red[7]) * (1.0f / (DD - 1));
  const float scale = 1.0f / (sqrtf(var) + LN_EPS);
  float4 gv = *(const float4*)(g + tid * 4);
  float4 bv = *(const float4*)(b + tid * 4);
  ushort4_t o;
  o[0] = f2bf(gv.x * d.x * scale + bv.x);
  o[1] = f2bf(gv.y * d.y * scale + bv.y);
  o[2] = f2bf(gv.z * d.z * scale + bv.z);
  o[3] = f2bf(gv.w * d.w * scale + bv.w);
  *(ushort4_t*)(out + (size_t)row * 2048 + tid * 4) = o;
  float4 tv = *(const float4*)(timep + (size_t)row * DD + tid * 4);
  ushort4_t to;
  to[0] = f2bf(tv.x); to[1] = f2bf(tv.y); to[2] = f2bf(tv.z); to[3] = f2bf(tv.w);
  *(ushort4_t*)(out + (size_t)row * 2048 + 1024 + tid * 4) = to;
}

// ---------------- ALL weight transposes in one launch (flat tile id ranges)
__global__ __launch_bounds__(256) void prep_weights(
    const float* __restrict__ Wq, const float* __restrict__ Wv,
    const float* __restrict__ Wk, const float* __restrict__ Wt,
    const float* __restrict__ Wo, const float* __restrict__ W1,
    const float* __restrict__ W2,
    unsigned short* __restrict__ WqvT, unsigned short* __restrict__ WkcT,
    unsigned short* __restrict__ WoT, unsigned short* __restrict__ W1T,
    unsigned short* __restrict__ W2T) {
  __shared__ float tile[32][33];
  int id = blockIdx.x;
  const float* W; unsigned short* WT; int N, ldo, xdim;
  if (id < 1024)      { W = Wq; WT = WqvT;                          N = 1024; ldo = 1024; xdim = 32; }
  else if (id < 2048) { W = Wv; WT = WqvT + (size_t)1024 * 1024;    N = 1024; ldo = 1024; xdim = 32; id -= 1024; }
  else if (id < 3072) { W = Wk; WT = WkcT;                          N = 1024; ldo = 2048; xdim = 32; id -= 2048; }
  else if (id < 4096) { W = Wt; WT = WkcT + 1024;                   N = 1024; ldo = 2048; xdim = 32; id -= 3072; }
  else if (id < 5120) { W = Wo; WT = WoT;                           N = 1024; ldo = 1024; xdim = 32; id -= 4096; }
  else if (id < 9216) { W = W1; WT = W1T;                           N = 4096; ldo = 1024; xdim = 128; id -= 5120; }
  else                { W = W2; WT = W2T;                           N = 1024; ldo = 4096; xdim = 32; id -= 9216; }
  const int bx = id % xdim, by = id / xdim;
  const int tx = threadIdx.x & 31, ty = threadIdx.x >> 5;
  const int n0 = bx * 32, k0 = by * 32;
#pragma unroll
  for (int i = 0; i < 32; i += 8)
    tile[ty + i][tx] = W[(size_t)(k0 + ty + i) * N + n0 + tx];
  __syncthreads();
#pragma unroll
  for (int i = 0; i < 32; i += 8)
    WT[(size_t)(n0 + ty + i) * ldo + k0 + tx] = f2bf(tile[tx][ty + i]);
}

// ---------------- v [8192][1024] bf16 -> vT [1024][8192] bf16, 64x64 LDS tiles
__global__ __launch_bounds__(256) void vtrans(const unsigned short* __restrict__ in,
                                              unsigned short* __restrict__ out) {
  __shared__ unsigned short tile[64][72];
  const int t = threadIdx.x;
  const int c0 = blockIdx.x * 64;
  const int r0 = blockIdx.y * 64;
  const int tx = t & 15, ty = t >> 4;
#pragma unroll
  for (int i = 0; i < 64; i += 16)
    *(ushort4_t*)&tile[ty + i][tx * 4] =
        *(const ushort4_t*)(in + (size_t)(r0 + ty + i) * 1024 + c0 + tx * 4);
  __syncthreads();
  const int cT = t >> 2, rq = (t & 3) * 16;
  ushort8 o0, o1;
#pragma unroll
  for (int j = 0; j < 8; ++j) o0[j] = tile[rq + j][cT];
#pragma unroll
  for (int j = 0; j < 8; ++j) o1[j] = tile[rq + 8 + j][cT];
  *(ushort8*)(out + (size_t)(c0 + cT) * 8192 + r0 + rq) = o0;
  *(ushort8*)(out + (size_t)(c0 + cT) * 8192 + r0 + rq + 8) = o1;
}

// ---------------- gate build + bias fold
__global__ __launch_bounds__(256) void gate_build(const int* __restrict__ mask,
                                                  const float* __restrict__ ml,
                                                  unsigned short* __restrict__ gate,
                                                  const float* __restrict__ bq,
                                                  const float* __restrict__ bv,
                                                  const float* __restrict__ bk,
                                                  const float* __restrict__ bt,
                                                  float* __restrict__ qvb,
                                                  float* __restrict__ kcb) {
  const int i = blockIdx.x * 256 + threadIdx.x;
  if (i < 3072) {
    if (i < 2048) qvb[i] = (i < 1024) ? bq[i] : bv[i - 1024];
    else kcb[i - 2048] = bk[i - 2048] + bt[i - 2048];
  }
  const size_t base = (size_t)i * 8;
  const int off = (int)(base & (SS * SS - 1));
  const int4* mp = (const int4*)(mask + base);
  const int4 m0 = mp[0], m1 = mp[1];
  const float4* lp = (const float4*)(ml + off);
  const float4 a = lp[0], b = lp[1];
  ushort8 o;
  o[0] = m0.x ? f2bf(1.0f / (1.0f + __expf(-a.x))) : 0;
  o[1] = m0.y ? f2bf(1.0f / (1.0f + __expf(-a.y))) : 0;
  o[2] = m0.z ? f2bf(1.0f / (1.0f + __expf(-a.z))) : 0;
  o[3] = m0.w ? f2bf(1.0f / (1.0f + __expf(-a.w))) : 0;
  o[4] = m1.x ? f2bf(1.0f / (1.0f + __expf(-b.x))) : 0;
  o[5] = m1.y ? f2bf(1.0f / (1.0f + __expf(-b.y))) : 0;
  o[6] = m1.z ? f2bf(1.0f / (1.0f + __expf(-b.z))) : 0;
  o[7] = m1.w ? f2bf(1.0f / (1.0f + __expf(-b.w))) : 0;
  *(ushort8*)(gate + base) = o;
}

// ---------------- gemm128: 128x128 tile, 256 threads (4 waves), 64KB LDS,
// 2 blocks/CU TLP, round-8 wait ladder. All GEMMs use this.
// EPI 0: bf16 ; EPI 1: +resid -> f32 ; EPI 2: gelu -> bf16 ;
// EPI 3: panel cols<1024 -> q (prescaled, ldc1024) ; >=1024 -> v (plain, ldc1024)
template <int EPI>
__global__ __launch_bounds__(256, 2) void gemm128(const unsigned short* __restrict__ A, int lda,
                                                  const unsigned short* __restrict__ BT,
                                                  const float* __restrict__ bias,
                                                  const float* __restrict__ resid,
                                                  void* __restrict__ Cout,
                                                  unsigned short* __restrict__ vOut,
                                                  int M, int N, int K) {
  __shared__ __align__(16) unsigned short smA[2 * 8192];
  __shared__ __align__(16) unsigned short smB[2 * 8192];

  const int tid = threadIdx.x;
  const int w = tid >> 6, lane = tid & 63;
  const int lr = lane & 15, lg = lane >> 4;
  const int wr = w >> 1, wn = w & 1;

  const int nb = N / 128;
  const int nwg = gridDim.x;
  int bid = blockIdx.x;
  bid = (bid & 7) * (nwg >> 3) + (bid >> 3);
  const int mb = bid / nb, nbk = bid % nb;

  const int uo = (lane * 16) ^ (lane & 32);
  const int srow = uo >> 6;
  const int scol = (uo & 63) >> 1;

  const unsigned short* pA[2];
  const unsigned short* pB[2];
#pragma unroll
  for (int j = 0; j < 2; ++j) {
    pA[j] = A + (size_t)(mb * 128 + (j * 4 + w) * 16 + srow) * lda + scol;
    pB[j] = BT + (size_t)(nbk * 128 + (j * 4 + w) * 16 + srow) * K + scol;
  }

  auto stA = [&](int kt, int ks, int j, int d) {
    __builtin_amdgcn_global_load_lds(
        (const AS1 void*)(pA[j] + (size_t)kt * 64 + ks * 32),
        (AS3 void*)(smA + d * 8192 + ks * 4096 + j * 2048 + w * 512), 16, 0, 0);
  };
  auto stB = [&](int kt, int ks, int j, int d) {
    __builtin_amdgcn_global_load_lds(
        (const AS1 void*)(pB[j] + (size_t)kt * 64 + ks * 32),
        (AS3 void*)(smB + d * 8192 + ks * 4096 + j * 2048 + w * 512), 16, 0, 0);
  };
  auto issue_half = [&](int t, int ks) {
    const int d = t & 1;
    stA(t, ks, 0, d); stA(t, ks, 1, d);
    stB(t, ks, 0, d); stB(t, ks, 1, d);
  };

  const int aoff = lr * 32 + ((lg * 8) ^ ((lr & 8) << 1));

  f32x4 acc[4][4] = {};
  const int NT = K >> 6;

  issue_half(0, 0);
  issue_half(0, 1);
  issue_half(1, 0);
  WAITVM(8);
  sbar();

  for (int kt = 0; kt < NT; ++kt) {
    const unsigned short* aD = smA + (kt & 1) * 8192;
    const unsigned short* bD = smB + (kt & 1) * 8192;
    const bool i1 = (kt + 1 < NT);
    const bool i2 = (kt + 2 < NT);
    bf16x8 af[4], bf[4];

    // phase A (ks0): stage (kt+1,k1); wait (kt,k1)
#pragma unroll
    for (int i = 0; i < 4; ++i)
      bf[i] = *(const bf16x8*)(bD + (wn * 4 + i) * 512 + aoff);
#pragma unroll
    for (int i = 0; i < 4; ++i)
      af[i] = *(const bf16x8*)(aD + (wr * 4 + i) * 512 + aoff);
    if (i1) issue_half(kt + 1, 1);
    if (i1) { WAITVM(8); } else { WAITVM(0); }
    sbar();
    __builtin_amdgcn_s_setprio(1);
#pragma unroll
    for (int mi = 0; mi < 4; ++mi)
#pragma unroll
      for (int ni = 0; ni < 4; ++ni)
        acc[mi][ni] = __builtin_amdgcn_mfma_f32_16x16x32_bf16(af[mi], bf[ni], acc[mi][ni], 0, 0, 0);
    __builtin_amdgcn_s_setprio(0);
    sbar();

    // phase B (ks1): stage (kt+2,k0); wait (kt+1,k0)
#pragma unroll
    for (int i = 0; i < 4; ++i)
      bf[i] = *(const bf16x8*)(bD + 4096 + (wn * 4 + i) * 512 + aoff);
#pragma unroll
    for (int i = 0; i < 4; ++i)
      af[i] = *(const bf16x8*)(aD + 4096 + (wr * 4 + i) * 512 + aoff);
    if (i2) issue_half(kt + 2, 0);
    if (i2) { WAITVM(8); } else if (i1) { WAITVM(4); } else { WAITVM(0); }
    sbar();
    __builtin_amdgcn_s_setprio(1);
#pragma unroll
    for (int mi = 0; mi < 4; ++mi)
#pragma unroll
      for (int ni = 0; ni < 4; ++ni)
        acc[mi][ni] = __builtin_amdgcn_mfma_f32_16x16x32_bf16(af[mi], bf[ni], acc[mi][ni], 0, 0, 0);
    __builtin_amdgcn_s_setprio(0);
    sbar();
  }

  // epilogue: ni innermost (full 128B lines)
  const int colb = nbk * 128 + wn * 64;
  const int rowb = mb * 128 + wr * 64;
  float bvv[4];
#pragma unroll
  for (int ni = 0; ni < 4; ++ni) bvv[ni] = bias[colb + ni * 16 + lr];

  if (EPI == 3 && colb >= 1024) {
#pragma unroll
    for (int mi = 0; mi < 4; ++mi) {
#pragma unroll
      for (int j = 0; j < 4; ++j) {
        const int row = rowb + mi * 16 + lg * 4 + j;
#pragma unroll
        for (int ni = 0; ni < 4; ++ni)
          vOut[(size_t)row * 1024 + (colb - 1024) + ni * 16 + lr] = f2bf(acc[mi][ni][j] + bvv[ni]);
      }
    }
  } else {
#pragma unroll
    for (int mi = 0; mi < 4; ++mi) {
#pragma unroll
      for (int j = 0; j < 4; ++j) {
        const int row = rowb + mi * 16 + lg * 4 + j;
#pragma unroll
        for (int ni = 0; ni < 4; ++ni) {
          const int col = colb + ni * 16 + lr;
          float vv = acc[mi][ni][j] + bvv[ni];
          if (EPI == 2) vv = gelu_f(vv);
          if (EPI == 1) {
            const size_t o = (size_t)row * N + col;
            ((float*)Cout)[o] = vv + resid[o];
          } else if (EPI == 3) {
            ((unsigned short*)Cout)[(size_t)row * 1024 + col] = f2bf(vv * QSCALE);
          } else {
            ((unsigned short*)Cout)[(size_t)row * N + col] = f2bf(vv);
          }
        }
      }
    }
  }
}

// ---------------- Fused attention v5 (round-10 proven) + launch_bounds(256,3) + T5
__global__ __launch_bounds__(256, 3) void attn4(const unsigned short* __restrict__ qb,
                                                const unsigned short* __restrict__ vT,
                                                const unsigned short* __restrict__ kcb,
                                                const unsigned short* __restrict__ gate,
                                                unsigned short* __restrict__ ctx) {
  __shared__ __align__(16) unsigned char smem[33280];
  float* pctx = (float*)smem;
  float* sumw = (float*)(smem + 32768);

  const int tid = threadIdx.x;
  const int w = tid >> 6, l = tid & 63;
  const int lr = l & 15, lg = l >> 4;
  const int virt = (blockIdx.x & 7) * 512 + (blockIdx.x >> 3);
  const int qt = virt & 15;
  const int h = (virt >> 4) & 15;
  const int b = virt >> 8;
  const int q0 = qt * 32;

  const unsigned short* qg = qb + (size_t)b * SS * DD + h * DKK;
  const unsigned short* kg = kcb + (size_t)b * SS * DD + h * DKK;
  const unsigned short* vg = vT + (size_t)(h * DKK) * 8192 + b * SS;
  const unsigned short* gg = gate + (size_t)b * SS * SS;
  unsigned short* cg = ctx + (size_t)b * SS * DD + h * DKK;

  bf16x8 qf[2][2];
#pragma unroll
  for (int mi = 0; mi < 2; ++mi)
#pragma unroll
    for (int ks = 0; ks < 2; ++ks)
      qf[mi][ks] = *(const bf16x8*)(qg + (size_t)(q0 + mi * 16 + lr) * DD + ks * 32 + lg * 8);

  f32x4 acc[2][4] = {};
  float ssum[2][4] = {};
  const int kb0 = w * 128;

#pragma unroll
  for (int it = 0; it < 4; ++it) {
    const int kbase = kb0 + it * 32;
    unsigned short* Pb = (unsigned short*)smem + w * 2560 + (it & 1) * 1280;  // [32][40]

    bf16x8 kf[2][2];
#pragma unroll
    for (int ni = 0; ni < 2; ++ni)
#pragma unroll
      for (int ks = 0; ks < 2; ++ks)
        kf[ni][ks] = *(const bf16x8*)(kg + (size_t)(kbase + ni * 16 + lr) * DD + ks * 32 + lg * 8);
    f32x4 sc[2][2] = {};
    __builtin_amdgcn_s_setprio(1);
#pragma unroll
    for (int ks = 0; ks < 2; ++ks)
#pragma unroll
      for (int mi = 0; mi < 2; ++mi)
#pragma unroll
        for (int ni = 0; ni < 2; ++ni)
          sc[mi][ni] = __builtin_amdgcn_mfma_f32_16x16x32_bf16(qf[mi][ks], kf[ni][ks], sc[mi][ni], 0, 0, 0);
    __builtin_amdgcn_s_setprio(0);

    bf16x8 vb[4];
#pragma unroll
    for (int dkg = 0; dkg < 4; ++dkg)
      vb[dkg] = *(const bf16x8*)(vg + (size_t)(dkg * 16 + lr) * 8192 + kbase + lg * 8);

#pragma unroll
    for (int mi = 0; mi < 2; ++mi)
#pragma unroll
      for (int ni = 0; ni < 2; ++ni)
#pragma unroll
        for (int j = 0; j < 4; ++j) {
          const int row = mi * 16 + lg * 4 + j;
          const unsigned short gu = gg[(size_t)(q0 + row) * SS + kbase + ni * 16 + lr];
          const float e = exp2f(sc[mi][ni][j]);
          ssum[mi][j] += gu ? e : 0.0f;
          Pb[row * 40 + ni * 16 + lr] = f2bf(e * bf2f(gu));
        }

    __builtin_amdgcn_s_setprio(1);
#pragma unroll
    for (int mi = 0; mi < 2; ++mi) {
      const bf16x8 pa = *(const bf16x8*)(Pb + (mi * 16 + lr) * 40 + lg * 8);
#pragma unroll
      for (int dkg = 0; dkg < 4; ++dkg)
        acc[mi][dkg] = __builtin_amdgcn_mfma_f32_16x16x32_bf16(pa, vb[dkg], acc[mi][dkg], 0, 0, 0);
    }
    __builtin_amdgcn_s_setprio(0);
  }

#pragma unroll
  for (int mi = 0; mi < 2; ++mi)
#pragma unroll
    for (int j = 0; j < 4; ++j) {
      float s = ssum[mi][j];
      s += __shfl_xor(s, 1);
      s += __shfl_xor(s, 2);
      s += __shfl_xor(s, 4);
      s += __shfl_xor(s, 8);
      if (lr == 0) sumw[w * 32 + mi * 16 + lg * 4 + j] = s;
    }
  __syncthreads();

#pragma unroll
  for (int mi = 0; mi < 2; ++mi)
#pragma unroll
    for (int dkg = 0; dkg < 4; ++dkg)
#pragma unroll
      for (int j = 0; j < 4; ++j)
        pctx[(size_t)w * 2048 + (mi * 16 + lg * 4 + j) * 64 + dkg * 16 + lr] = acc[mi][dkg][j];
  __syncthreads();

  {
    const int row = tid >> 3;
    const int dk0 = (tid & 7) * 8;
    const float tot = sumw[row] + sumw[32 + row] + sumw[64 + row] + sumw[96 + row];
    const float inv = 1.0f / fmaxf(tot, 1e-30f);
    float vsum[8];
#pragma unroll
    for (int c = 0; c < 8; ++c) vsum[c] = 0.0f;
#pragma unroll
    for (int ww = 0; ww < 4; ++ww) {
      const float* p = pctx + (size_t)ww * 2048 + row * 64 + dk0;
      f32x4 a = *(const f32x4*)p;
      f32x4 bq = *(const f32x4*)(p + 4);
#pragma unroll
      for (int c = 0; c < 4; ++c) { vsum[c] += a[c]; vsum[4 + c] += bq[c]; }
    }
    ushort8 o;
#pragma unroll
    for (int c = 0; c < 8; ++c) o[c] = f2bf(vsum[c] * inv);
    *(ushort8*)(cg + (size_t)(q0 + row) * DD + dk0) = o;
  }
}

// ----------------------------------------------------------------------------
extern "C" void kernel_launch(void* const* d_in, const int* in_sizes, int n_in,
                              void* d_out, int out_size, void* d_ws, size_t ws_size,
                              hipStream_t stream) {
  (void)in_sizes; (void)n_in; (void)out_size; (void)ws_size;
  const float* x    = (const float*)d_in[0];
  const float* timep= (const float*)d_in[1];
  const float* Wq = (const float*)d_in[2];  const float* bq = (const float*)d_in[3];
  const float* Wk = (const float*)d_in[4];  const float* bk = (const float*)d_in[5];
  const float* Wt = (const float*)d_in[6];  const float* bt = (const float*)d_in[7];
  const float* Wv = (const float*)d_in[8];  const float* bv = (const float*)d_in[9];
  const float* Wo = (const float*)d_in[10]; const float* bo = (const float*)d_in[11];
  const float* W1 = (const float*)d_in[12]; const float* b1 = (const float*)d_in[13];
  const float* W2 = (const float*)d_in[14]; const float* b2 = (const float*)d_in[15];
  const float* ln1g = (const float*)d_in[16]; const float* ln1b = (const float*)d_in[17];
  const float* ln2g = (const float*)d_in[18]; const float* ln2b = (const float*)d_in[19];
  const float* ml   = (const float*)d_in[20];
  const int*   mask = (const int*)d_in[21];
  float* out = (float*)d_out;

  char* w = (char*)d_ws;
  auto alloc = [&](size_t sz) { char* p = w; w += (sz + 255) & ~(size_t)255; return p; };
  const int MT = BB * SS;  // 8192 rows

  unsigned short* WqvT = (unsigned short*)alloc((size_t)2048 * 1024 * 2);
  unsigned short* WkcT = (unsigned short*)alloc((size_t)1024 * 2048 * 2);
  unsigned short* WoT  = (unsigned short*)alloc((size_t)DD * DD * 2);
  unsigned short* W1T  = (unsigned short*)alloc((size_t)DD * DFFN * 2);
  unsigned short* W2T  = (unsigned short*)alloc((size_t)DFFN * DD * 2);
  float* qvb = (float*)alloc(2048 * 4);
  float* kcbias = (float*)alloc(1024 * 4);
  unsigned short* gateb = (unsigned short*)alloc((size_t)BB * SS * SS * 2);
  unsigned short* xt2 = (unsigned short*)alloc((size_t)MT * 2048 * 2);  // [xn | time]
  unsigned short* qbuf = (unsigned short*)alloc((size_t)MT * DD * 2);   // q (prescaled)
  unsigned short* vbuf = (unsigned short*)alloc((size_t)MT * DD * 2);   // v
  unsigned short* vTb = (unsigned short*)alloc((size_t)DD * MT * 2);    // v^T
  unsigned short* kcb = (unsigned short*)alloc((size_t)MT * DD * 2);    // k1+k2
  float*          x2  = (float*)alloc((size_t)MT * DD * 4);
  unsigned short* hb  = (unsigned short*)alloc((size_t)MT * DFFN * 2);
  unsigned short* ctx = xt2;
  unsigned short* xn2 = xt2;

  // merged prep
  prep_weights<<<dim3(13312), 256, 0, stream>>>(Wq, Wv, Wk, Wt, Wo, W1, W2,
                                                WqvT, WkcT, WoT, W1T, W2T);
  gate_build<<<dim3(BB * SS * SS / 8 / 256), 256, 0, stream>>>(mask, ml, gateb,
                                                               bq, bv, bk, bt, qvb, kcbias);
  ln_time<<<dim3(MT), 256, 0, stream>>>(x, ln1g, ln1b, timep, xt2);

  // all GEMMs on gemm128 (2 blocks/CU TLP)
  gemm128<3><<<dim3(1024), 256, 0, stream>>>(xt2, 2048, WqvT, qvb, nullptr, (void*)qbuf, vbuf, MT, 2048, 1024);
  vtrans<<<dim3(16, 128), 256, 0, stream>>>(vbuf, vTb);
  gemm128<0><<<dim3(512), 256, 0, stream>>>(xt2, 2048, WkcT, kcbias, nullptr, (void*)kcb, nullptr, MT, 1024, 2048);

  attn4<<<dim3(BB * HH * 16), 256, 0, stream>>>(qbuf, vTb, kcb, gateb, ctx);

  gemm128<1><<<dim3(512), 256, 0, stream>>>(ctx, 1024, WoT, bo, x, (void*)x2, nullptr, MT, 1024, 1024);
  ln_kernel<<<dim3(MT), 256, 0, stream>>>(x2, ln2g, ln2b, xn2, 1024);
  gemm128<2><<<dim3(2048), 256, 0, stream>>>(xn2, 1024, W1T, b1, nullptr, (void*)hb, nullptr, MT, 4096, 1024);
  gemm128<1><<<dim3(512), 256, 0, stream>>>(hb, 4096, W2T, b2, x2, (void*)out, nullptr, MT, 1024, 4096);
}

// Round 15
// 422.918 us; speedup vs baseline: 1.2183x; 1.2183x over previous
//
#include <hip/hip_runtime.h>

#define BB   16
#define SS   512
#define DD   1024
#define HH   16
#define DKK  64
#define DFFN 4096
#define LN_EPS 1e-6f
#define QSCALE 0.18033688011112042f   // 0.125 * log2(e)

typedef __attribute__((ext_vector_type(8))) __bf16 bf16x8;
typedef __attribute__((ext_vector_type(4))) float f32x4;
typedef __attribute__((ext_vector_type(8))) unsigned short ushort8;
typedef __attribute__((ext_vector_type(4))) unsigned short ushort4_t;

#define AS1 __attribute__((address_space(1)))
#define AS3 __attribute__((address_space(3)))

__device__ __forceinline__ unsigned short f2bf(float f) {
  unsigned int u = __float_as_uint(f);
  u += 0x7FFFu + ((u >> 16) & 1u);   // round-nearest-even
  return (unsigned short)(u >> 16);
}
__device__ __forceinline__ float bf2f(unsigned short u) {
  return __uint_as_float(((unsigned int)u) << 16);
}

// exact: 0.5x(1+tanh(t)) == x * sigmoid(2t)
__device__ __forceinline__ float gelu_f(float x) {
  float t = 0.7978845608028654f * (x + 0.044715f * x * x * x);
  return x / (1.0f + __expf(-2.0f * t));
}

__device__ __forceinline__ void sbar() {
  __builtin_amdgcn_sched_barrier(0);
  __builtin_amdgcn_s_barrier();
  __builtin_amdgcn_sched_barrier(0);
}
#define WAITVM(N)                                         \
  do {                                                    \
    __builtin_amdgcn_sched_barrier(0);                    \
    asm volatile("s_waitcnt vmcnt(" #N ")" ::: "memory"); \
    __builtin_amdgcn_sched_barrier(0);                    \
  } while (0)

// ---------------- LayerNorm: fp32 in -> bf16 out (strided out)
__global__ __launch_bounds__(256) void ln_kernel(const float* __restrict__ x,
                                                 const float* __restrict__ g,
                                                 const float* __restrict__ b,
                                                 unsigned short* __restrict__ out, int ldo) {
  const int row = blockIdx.x;
  const int tid = threadIdx.x;
  const float* xr = x + (size_t)row * DD;
  float4 v = *(const float4*)(xr + tid * 4);
  float s = v.x + v.y + v.z + v.w;
#pragma unroll
  for (int off = 1; off < 64; off <<= 1) s += __shfl_xor(s, off);
  __shared__ float red[8];
  const int wid = tid >> 6, l = tid & 63;
  if (l == 0) red[wid] = s;
  __syncthreads();
  const float mean = (red[0] + red[1] + red[2] + red[3]) * (1.0f / DD);
  float4 d;
  d.x = v.x - mean; d.y = v.y - mean; d.z = v.z - mean; d.w = v.w - mean;
  float ss = d.x * d.x + d.y * d.y + d.z * d.z + d.w * d.w;
#pragma unroll
  for (int off = 1; off < 64; off <<= 1) ss += __shfl_xor(ss, off);
  if (l == 0) red[4 + wid] = ss;
  __syncthreads();
  const float var = (red[4] + red[5] + red[6] + red[7]) * (1.0f / (DD - 1));
  const float scale = 1.0f / (sqrtf(var) + LN_EPS);
  float4 gv = *(const float4*)(g + tid * 4);
  float4 bv = *(const float4*)(b + tid * 4);
  ushort4_t o;
  o[0] = f2bf(gv.x * d.x * scale + bv.x);
  o[1] = f2bf(gv.y * d.y * scale + bv.y);
  o[2] = f2bf(gv.z * d.z * scale + bv.z);
  o[3] = f2bf(gv.w * d.w * scale + bv.w);
  *(ushort4_t*)(out + (size_t)row * ldo + tid * 4) = o;
}

// ---------------- ln1(x) AND bf16(time) into xt2[row][0..1024 | 1024..2048]
__global__ __launch_bounds__(256) void ln_time(const float* __restrict__ x,
                                               const float* __restrict__ g,
                                               const float* __restrict__ b,
                                               const float* __restrict__ timep,
                                               unsigned short* __restrict__ out) {
  const int row = blockIdx.x;
  const int tid = threadIdx.x;
  const float* xr = x + (size_t)row * DD;
  float4 v = *(const float4*)(xr + tid * 4);
  float s = v.x + v.y + v.z + v.w;
#pragma unroll
  for (int off = 1; off < 64; off <<= 1) s += __shfl_xor(s, off);
  __shared__ float red[8];
  const int wid = tid >> 6, l = tid & 63;
  if (l == 0) red[wid] = s;
  __syncthreads();
  const float mean = (red[0] + red[1] + red[2] + red[3]) * (1.0f / DD);
  float4 d;
  d.x = v.x - mean; d.y = v.y - mean; d.z = v.z - mean; d.w = v.w - mean;
  float ss = d.x * d.x + d.y * d.y + d.z * d.z + d.w * d.w;
#pragma unroll
  for (int off = 1; off < 64; off <<= 1) ss += __shfl_xor(ss, off);
  if (l == 0) red[4 + wid] = ss;
  __syncthreads();
  const float var = (red[4] + red[5] + red[6] + red[7]) * (1.0f / (DD - 1));
  const float scale = 1.0f / (sqrtf(var) + LN_EPS);
  float4 gv = *(const float4*)(g + tid * 4);
  float4 bv = *(const float4*)(b + tid * 4);
  ushort4_t o;
  o[0] = f2bf(gv.x * d.x * scale + bv.x);
  o[1] = f2bf(gv.y * d.y * scale + bv.y);
  o[2] = f2bf(gv.z * d.z * scale + bv.z);
  o[3] = f2bf(gv.w * d.w * scale + bv.w);
  *(ushort4_t*)(out + (size_t)row * 2048 + tid * 4) = o;
  float4 tv = *(const float4*)(timep + (size_t)row * DD + tid * 4);
  ushort4_t to;
  to[0] = f2bf(tv.x); to[1] = f2bf(tv.y); to[2] = f2bf(tv.z); to[3] = f2bf(tv.w);
  *(ushort4_t*)(out + (size_t)row * 2048 + 1024 + tid * 4) = to;
}

// ---------------- ALL weight transposes in one launch (flat tile id ranges)
__global__ __launch_bounds__(256) void prep_weights(
    const float* __restrict__ Wq, const float* __restrict__ Wv,
    const float* __restrict__ Wk, const float* __restrict__ Wt,
    const float* __restrict__ Wo, const float* __restrict__ W1,
    const float* __restrict__ W2,
    unsigned short* __restrict__ WqvT, unsigned short* __restrict__ WkcT,
    unsigned short* __restrict__ WoT, unsigned short* __restrict__ W1T,
    unsigned short* __restrict__ W2T) {
  __shared__ float tile[32][33];
  int id = blockIdx.x;
  const float* W; unsigned short* WT; int N, ldo, xdim;
  if (id < 1024)      { W = Wq; WT = WqvT;                          N = 1024; ldo = 1024; xdim = 32; }
  else if (id < 2048) { W = Wv; WT = WqvT + (size_t)1024 * 1024;    N = 1024; ldo = 1024; xdim = 32; id -= 1024; }
  else if (id < 3072) { W = Wk; WT = WkcT;                          N = 1024; ldo = 2048; xdim = 32; id -= 2048; }
  else if (id < 4096) { W = Wt; WT = WkcT + 1024;                   N = 1024; ldo = 2048; xdim = 32; id -= 3072; }
  else if (id < 5120) { W = Wo; WT = WoT;                           N = 1024; ldo = 1024; xdim = 32; id -= 4096; }
  else if (id < 9216) { W = W1; WT = W1T;                           N = 4096; ldo = 1024; xdim = 128; id -= 5120; }
  else                { W = W2; WT = W2T;                           N = 1024; ldo = 4096; xdim = 32; id -= 9216; }
  const int bx = id % xdim, by = id / xdim;
  const int tx = threadIdx.x & 31, ty = threadIdx.x >> 5;
  const int n0 = bx * 32, k0 = by * 32;
#pragma unroll
  for (int i = 0; i < 32; i += 8)
    tile[ty + i][tx] = W[(size_t)(k0 + ty + i) * N + n0 + tx];
  __syncthreads();
#pragma unroll
  for (int i = 0; i < 32; i += 8)
    WT[(size_t)(n0 + ty + i) * ldo + k0 + tx] = f2bf(tile[tx][ty + i]);
}

// ---------------- v [8192][1024] bf16 -> vT [1024][8192] bf16, 64x64 LDS tiles
__global__ __launch_bounds__(256) void vtrans(const unsigned short* __restrict__ in,
                                              unsigned short* __restrict__ out) {
  __shared__ unsigned short tile[64][72];
  const int t = threadIdx.x;
  const int c0 = blockIdx.x * 64;
  const int r0 = blockIdx.y * 64;
  const int tx = t & 15, ty = t >> 4;
#pragma unroll
  for (int i = 0; i < 64; i += 16)
    *(ushort4_t*)&tile[ty + i][tx * 4] =
        *(const ushort4_t*)(in + (size_t)(r0 + ty + i) * 1024 + c0 + tx * 4);
  __syncthreads();
  const int cT = t >> 2, rq = (t & 3) * 16;
  ushort8 o0, o1;
#pragma unroll
  for (int j = 0; j < 8; ++j) o0[j] = tile[rq + j][cT];
#pragma unroll
  for (int j = 0; j < 8; ++j) o1[j] = tile[rq + 8 + j][cT];
  *(ushort8*)(out + (size_t)(c0 + cT) * 8192 + r0 + rq) = o0;
  *(ushort8*)(out + (size_t)(c0 + cT) * 8192 + r0 + rq + 8) = o1;
}

// ---------------- gate build + bias fold
__global__ __launch_bounds__(256) void gate_build(const int* __restrict__ mask,
                                                  const float* __restrict__ ml,
                                                  unsigned short* __restrict__ gate,
                                                  const float* __restrict__ bq,
                                                  const float* __restrict__ bv,
                                                  const float* __restrict__ bk,
                                                  const float* __restrict__ bt,
                                                  float* __restrict__ qvb,
                                                  float* __restrict__ kcb) {
  const int i = blockIdx.x * 256 + threadIdx.x;
  if (i < 3072) {
    if (i < 2048) qvb[i] = (i < 1024) ? bq[i] : bv[i - 1024];
    else kcb[i - 2048] = bk[i - 2048] + bt[i - 2048];
  }
  const size_t base = (size_t)i * 8;
  const int off = (int)(base & (SS * SS - 1));
  const int4* mp = (const int4*)(mask + base);
  const int4 m0 = mp[0], m1 = mp[1];
  const float4* lp = (const float4*)(ml + off);
  const float4 a = lp[0], b = lp[1];
  ushort8 o;
  o[0] = m0.x ? f2bf(1.0f / (1.0f + __expf(-a.x))) : 0;
  o[1] = m0.y ? f2bf(1.0f / (1.0f + __expf(-a.y))) : 0;
  o[2] = m0.z ? f2bf(1.0f / (1.0f + __expf(-a.z))) : 0;
  o[3] = m0.w ? f2bf(1.0f / (1.0f + __expf(-a.w))) : 0;
  o[4] = m1.x ? f2bf(1.0f / (1.0f + __expf(-b.x))) : 0;
  o[5] = m1.y ? f2bf(1.0f / (1.0f + __expf(-b.y))) : 0;
  o[6] = m1.z ? f2bf(1.0f / (1.0f + __expf(-b.z))) : 0;
  o[7] = m1.w ? f2bf(1.0f / (1.0f + __expf(-b.w))) : 0;
  *(ushort8*)(gate + base) = o;
}

// ---------------- deep-pipelined GEMM (round-8 proven ladder), BM=256
// EPI 2: gelu -> bf16 ; EPI 3: block cols<1024 -> q (prescaled) ; >=1024 -> v
template <int BM, int EPI>
__global__ __launch_bounds__(512, 2) void gemm8p(const unsigned short* __restrict__ A, int lda,
                                                 const unsigned short* __restrict__ BT,
                                                 const float* __restrict__ bias,
                                                 const float* __restrict__ resid,
                                                 void* __restrict__ Cout,
                                                 unsigned short* __restrict__ vOut,
                                                 int M, int N, int K) {
  constexpr int MI = BM / 32;
  constexpr int ASUB = BM / 16;
  constexpr int AHALF = BM * 32;
  constexpr int ABUF = BM * 64;
  constexpr int ACALL = BM / 128;

  __shared__ __align__(16) unsigned short smA[2 * ABUF];
  __shared__ __align__(16) unsigned short smB[2 * 16384];

  const int tid = threadIdx.x;
  const int w = tid >> 6, lane = tid & 63;
  const int lr = lane & 15, lg = lane >> 4;
  const int wr = w >> 2, wn = w & 3;

  const int nb = N / 256;
  const int nwg = gridDim.x;
  int bid = blockIdx.x;
  bid = (bid & 7) * (nwg >> 3) + (bid >> 3);
  const int mb = bid / nb, nbk = bid % nb;

  const int uo = (lane * 16) ^ (lane & 32);
  const int srow = uo >> 6;
  const int scol = (uo & 63) >> 1;

  const unsigned short* pA[2];
  const unsigned short* pB[2];
#pragma unroll
  for (int j = 0; j < ACALL; ++j)
    pA[j] = A + (size_t)(mb * BM + (j * 8 + w) * 16 + srow) * lda + scol;
  if (ACALL == 1) pA[1] = pA[0];
#pragma unroll
  for (int j = 0; j < 2; ++j)
    pB[j] = BT + (size_t)(nbk * 256 + (j * 8 + w) * 16 + srow) * K + scol;

  auto stA = [&](int kt, int ks, int j, int d) {
    __builtin_amdgcn_global_load_lds(
        (const AS1 void*)(pA[j] + (size_t)kt * 64 + ks * 32),
        (AS3 void*)(smA + d * ABUF + ks * AHALF + j * 4096 + w * 512), 16, 0, 0);
  };
  auto stB = [&](int kt, int ks, int j, int d) {
    __builtin_amdgcn_global_load_lds(
        (const AS1 void*)(pB[j] + (size_t)kt * 64 + ks * 32),
        (AS3 void*)(smB + d * 16384 + ks * 8192 + j * 4096 + w * 512), 16, 0, 0);
  };
  auto issue_half = [&](int t, int ks) {
    const int d = t & 1;
#pragma unroll
    for (int j = 0; j < ACALL; ++j) stA(t, ks, j, d);
    stB(t, ks, 0, d);
    stB(t, ks, 1, d);
  };

  const int aoff = lr * 32 + ((lg * 8) ^ ((lr & 8) << 1));

  f32x4 acc[MI][4] = {};
  const int NT = K >> 6;

  issue_half(0, 0);
  issue_half(0, 1);
  issue_half(1, 0);
  if constexpr (ACALL == 2) { WAITVM(8); } else { WAITVM(6); }
  sbar();

  for (int kt = 0; kt < NT; ++kt) {
    const unsigned short* aD = smA + (kt & 1) * ABUF;
    const unsigned short* bD = smB + (kt & 1) * 16384;
    const bool i1 = (kt + 1 < NT);
    const bool i2 = (kt + 2 < NT);
    bf16x8 af[4], bf[4];

    // phase A
#pragma unroll
    for (int i = 0; i < 4; ++i)
      bf[i] = *(const bf16x8*)(bD + (wn * 4 + i) * 512 + aoff);
#pragma unroll
    for (int i = 0; i < 4; ++i)
      af[i] = *(const bf16x8*)(aD + (wr * MI + i) * 512 + aoff);
    if (i1) issue_half(kt + 1, 1);
    if constexpr (ACALL == 1) {
      if (i1) { WAITVM(6); } else { WAITVM(0); }
    }
    sbar();
    __builtin_amdgcn_s_setprio(1);
#pragma unroll
    for (int mi = 0; mi < 4; ++mi)
#pragma unroll
      for (int ni = 0; ni < 4; ++ni)
        acc[mi][ni] = __builtin_amdgcn_mfma_f32_16x16x32_bf16(af[mi], bf[ni], acc[mi][ni], 0, 0, 0);
    __builtin_amdgcn_s_setprio(0);
    sbar();

    if constexpr (ACALL == 2) {
      // phase B
#pragma unroll
      for (int i = 0; i < 4; ++i)
        af[i] = *(const bf16x8*)(aD + (wr * MI + 4 + i) * 512 + aoff);
      if (i1) { WAITVM(8); } else { WAITVM(0); }
      sbar();
      __builtin_amdgcn_s_setprio(1);
#pragma unroll
      for (int mi = 0; mi < 4; ++mi)
#pragma unroll
        for (int ni = 0; ni < 4; ++ni)
          acc[4 + mi][ni] = __builtin_amdgcn_mfma_f32_16x16x32_bf16(af[mi], bf[ni], acc[4 + mi][ni], 0, 0, 0);
      __builtin_amdgcn_s_setprio(0);
      sbar();
    }

    // phase C
#pragma unroll
    for (int i = 0; i < 4; ++i)
      bf[i] = *(const bf16x8*)(bD + (16 + wn * 4 + i) * 512 + aoff);
#pragma unroll
    for (int i = 0; i < 4; ++i)
      af[i] = *(const bf16x8*)(aD + (ASUB + wr * MI + i) * 512 + aoff);
    if (i2) issue_half(kt + 2, 0);
    if constexpr (ACALL == 1) {
      if (i2) { WAITVM(6); } else { WAITVM(3); }
    }
    sbar();
    __builtin_amdgcn_s_setprio(1);
#pragma unroll
    for (int mi = 0; mi < 4; ++mi)
#pragma unroll
      for (int ni = 0; ni < 4; ++ni)
        acc[mi][ni] = __builtin_amdgcn_mfma_f32_16x16x32_bf16(af[mi], bf[ni], acc[mi][ni], 0, 0, 0);
    __builtin_amdgcn_s_setprio(0);
    sbar();

    if constexpr (ACALL == 2) {
      // phase D
#pragma unroll
      for (int i = 0; i < 4; ++i)
        af[i] = *(const bf16x8*)(aD + (ASUB + wr * MI + 4 + i) * 512 + aoff);
      if (i2) { WAITVM(8); } else { WAITVM(4); }
      sbar();
      __builtin_amdgcn_s_setprio(1);
#pragma unroll
      for (int mi = 0; mi < 4; ++mi)
#pragma unroll
        for (int ni = 0; ni < 4; ++ni)
          acc[4 + mi][ni] = __builtin_amdgcn_mfma_f32_16x16x32_bf16(af[mi], bf[ni], acc[4 + mi][ni], 0, 0, 0);
      __builtin_amdgcn_s_setprio(0);
      sbar();
    }
  }

  const int colb = nbk * 256 + wn * 64;
  const int rowb = mb * BM + wr * (BM / 2);
  float bvv[4];
#pragma unroll
  for (int ni = 0; ni < 4; ++ni) bvv[ni] = bias[colb + ni * 16 + lr];

  if (EPI == 3 && colb >= 1024) {
#pragma unroll
    for (int mi = 0; mi < MI; ++mi) {
#pragma unroll
      for (int j = 0; j < 4; ++j) {
        const int row = rowb + mi * 16 + lg * 4 + j;
#pragma unroll
        for (int ni = 0; ni < 4; ++ni)
          vOut[(size_t)row * 1024 + (colb - 1024) + ni * 16 + lr] = f2bf(acc[mi][ni][j] + bvv[ni]);
      }
    }
  } else {
#pragma unroll
    for (int mi = 0; mi < MI; ++mi) {
#pragma unroll
      for (int j = 0; j < 4; ++j) {
        const int row = rowb + mi * 16 + lg * 4 + j;
#pragma unroll
        for (int ni = 0; ni < 4; ++ni) {
          const int col = colb + ni * 16 + lr;
          float vv = acc[mi][ni][j] + bvv[ni];
          if (EPI == 2) vv = gelu_f(vv);
          if (EPI == 1) {
            const size_t o = (size_t)row * N + col;
            ((float*)Cout)[o] = vv + resid[o];
          } else if (EPI == 3) {
            ((unsigned short*)Cout)[(size_t)row * 1024 + col] = f2bf(vv * QSCALE);
          } else {
            ((unsigned short*)Cout)[(size_t)row * N + col] = f2bf(vv);
          }
        }
      }
    }
  }
}

// ---------------- gemm128: 128x128 tile, 256 threads (4 waves), 64KB LDS
template <int EPI>
__global__ __launch_bounds__(256, 2) void gemm128(const unsigned short* __restrict__ A, int lda,
                                                  const unsigned short* __restrict__ BT,
                                                  const float* __restrict__ bias,
                                                  const float* __restrict__ resid,
                                                  void* __restrict__ Cout,
                                                  int M, int N, int K) {
  __shared__ __align__(16) unsigned short smA[2 * 8192];
  __shared__ __align__(16) unsigned short smB[2 * 8192];

  const int tid = threadIdx.x;
  const int w = tid >> 6, lane = tid & 63;
  const int lr = lane & 15, lg = lane >> 4;
  const int wr = w >> 1, wn = w & 1;

  const int nb = N / 128;
  const int nwg = gridDim.x;
  int bid = blockIdx.x;
  bid = (bid & 7) * (nwg >> 3) + (bid >> 3);
  const int mb = bid / nb, nbk = bid % nb;

  const int uo = (lane * 16) ^ (lane & 32);
  const int srow = uo >> 6;
  const int scol = (uo & 63) >> 1;

  const unsigned short* pA[2];
  const unsigned short* pB[2];
#pragma unroll
  for (int j = 0; j < 2; ++j) {
    pA[j] = A + (size_t)(mb * 128 + (j * 4 + w) * 16 + srow) * lda + scol;
    pB[j] = BT + (size_t)(nbk * 128 + (j * 4 + w) * 16 + srow) * K + scol;
  }

  auto stA = [&](int kt, int ks, int j, int d) {
    __builtin_amdgcn_global_load_lds(
        (const AS1 void*)(pA[j] + (size_t)kt * 64 + ks * 32),
        (AS3 void*)(smA + d * 8192 + ks * 4096 + j * 2048 + w * 512), 16, 0, 0);
  };
  auto stB = [&](int kt, int ks, int j, int d) {
    __builtin_amdgcn_global_load_lds(
        (const AS1 void*)(pB[j] + (size_t)kt * 64 + ks * 32),
        (AS3 void*)(smB + d * 8192 + ks * 4096 + j * 2048 + w * 512), 16, 0, 0);
  };
  auto issue_half = [&](int t, int ks) {
    const int d = t & 1;
    stA(t, ks, 0, d); stA(t, ks, 1, d);
    stB(t, ks, 0, d); stB(t, ks, 1, d);
  };

  const int aoff = lr * 32 + ((lg * 8) ^ ((lr & 8) << 1));

  f32x4 acc[4][4] = {};
  const int NT = K >> 6;

  issue_half(0, 0);
  issue_half(0, 1);
  issue_half(1, 0);
  WAITVM(8);
  sbar();

  for (int kt = 0; kt < NT; ++kt) {
    const unsigned short* aD = smA + (kt & 1) * 8192;
    const unsigned short* bD = smB + (kt & 1) * 8192;
    const bool i1 = (kt + 1 < NT);
    const bool i2 = (kt + 2 < NT);
    bf16x8 af[4], bf[4];

    // phase A (ks0): stage (kt+1,k1); wait (kt,k1)
#pragma unroll
    for (int i = 0; i < 4; ++i)
      bf[i] = *(const bf16x8*)(bD + (wn * 4 + i) * 512 + aoff);
#pragma unroll
    for (int i = 0; i < 4; ++i)
      af[i] = *(const bf16x8*)(aD + (wr * 4 + i) * 512 + aoff);
    if (i1) issue_half(kt + 1, 1);
    if (i1) { WAITVM(8); } else { WAITVM(0); }
    sbar();
    __builtin_amdgcn_s_setprio(1);
#pragma unroll
    for (int mi = 0; mi < 4; ++mi)
#pragma unroll
      for (int ni = 0; ni < 4; ++ni)
        acc[mi][ni] = __builtin_amdgcn_mfma_f32_16x16x32_bf16(af[mi], bf[ni], acc[mi][ni], 0, 0, 0);
    __builtin_amdgcn_s_setprio(0);
    sbar();

    // phase B (ks1): stage (kt+2,k0); wait (kt+1,k0)
#pragma unroll
    for (int i = 0; i < 4; ++i)
      bf[i] = *(const bf16x8*)(bD + 4096 + (wn * 4 + i) * 512 + aoff);
#pragma unroll
    for (int i = 0; i < 4; ++i)
      af[i] = *(const bf16x8*)(aD + 4096 + (wr * 4 + i) * 512 + aoff);
    if (i2) issue_half(kt + 2, 0);
    if (i2) { WAITVM(8); } else if (i1) { WAITVM(4); } else { WAITVM(0); }
    sbar();
    __builtin_amdgcn_s_setprio(1);
#pragma unroll
    for (int mi = 0; mi < 4; ++mi)
#pragma unroll
      for (int ni = 0; ni < 4; ++ni)
        acc[mi][ni] = __builtin_amdgcn_mfma_f32_16x16x32_bf16(af[mi], bf[ni], acc[mi][ni], 0, 0, 0);
    __builtin_amdgcn_s_setprio(0);
    sbar();
  }

  const int colb = nbk * 128 + wn * 64;
  const int rowb = mb * 128 + wr * 64;
  float bvv[4];
#pragma unroll
  for (int ni = 0; ni < 4; ++ni) bvv[ni] = bias[colb + ni * 16 + lr];
#pragma unroll
  for (int mi = 0; mi < 4; ++mi) {
#pragma unroll
    for (int j = 0; j < 4; ++j) {
      const int row = rowb + mi * 16 + lg * 4 + j;
#pragma unroll
      for (int ni = 0; ni < 4; ++ni) {
        const int col = colb + ni * 16 + lr;
        const float vv = acc[mi][ni][j] + bvv[ni];
        if (EPI == 1) {
          const size_t o = (size_t)row * N + col;
          ((float*)Cout)[o] = vv + resid[o];
        } else {
          ((unsigned short*)Cout)[(size_t)row * N + col] = f2bf(vv);
        }
      }
    }
  }
}

// ---------------- Fused attention v5 (round-13 proven) + T5 setprio only
__global__ __launch_bounds__(256) void attn4(const unsigned short* __restrict__ qb,
                                             const unsigned short* __restrict__ vT,
                                             const unsigned short* __restrict__ kcb,
                                             const unsigned short* __restrict__ gate,
                                             unsigned short* __restrict__ ctx) {
  __shared__ __align__(16) unsigned char smem[33280];
  float* pctx = (float*)smem;
  float* sumw = (float*)(smem + 32768);

  const int tid = threadIdx.x;
  const int w = tid >> 6, l = tid & 63;
  const int lr = l & 15, lg = l >> 4;
  const int virt = (blockIdx.x & 7) * 512 + (blockIdx.x >> 3);
  const int qt = virt & 15;
  const int h = (virt >> 4) & 15;
  const int b = virt >> 8;
  const int q0 = qt * 32;

  const unsigned short* qg = qb + (size_t)b * SS * DD + h * DKK;
  const unsigned short* kg = kcb + (size_t)b * SS * DD + h * DKK;
  const unsigned short* vg = vT + (size_t)(h * DKK) * 8192 + b * SS;
  const unsigned short* gg = gate + (size_t)b * SS * SS;
  unsigned short* cg = ctx + (size_t)b * SS * DD + h * DKK;

  bf16x8 qf[2][2];
#pragma unroll
  for (int mi = 0; mi < 2; ++mi)
#pragma unroll
    for (int ks = 0; ks < 2; ++ks)
      qf[mi][ks] = *(const bf16x8*)(qg + (size_t)(q0 + mi * 16 + lr) * DD + ks * 32 + lg * 8);

  f32x4 acc[2][4] = {};
  float ssum[2][4] = {};
  const int kb0 = w * 128;

#pragma unroll
  for (int it = 0; it < 4; ++it) {
    const int kbase = kb0 + it * 32;
    unsigned short* Pb = (unsigned short*)smem + w * 2560 + (it & 1) * 1280;  // [32][40]

    bf16x8 kf[2][2];
#pragma unroll
    for (int ni = 0; ni < 2; ++ni)
#pragma unroll
      for (int ks = 0; ks < 2; ++ks)
        kf[ni][ks] = *(const bf16x8*)(kg + (size_t)(kbase + ni * 16 + lr) * DD + ks * 32 + lg * 8);
    f32x4 sc[2][2] = {};
    __builtin_amdgcn_s_setprio(1);
#pragma unroll
    for (int ks = 0; ks < 2; ++ks)
#pragma unroll
      for (int mi = 0; mi < 2; ++mi)
#pragma unroll
        for (int ni = 0; ni < 2; ++ni)
          sc[mi][ni] = __builtin_amdgcn_mfma_f32_16x16x32_bf16(qf[mi][ks], kf[ni][ks], sc[mi][ni], 0, 0, 0);
    __builtin_amdgcn_s_setprio(0);

    bf16x8 vb[4];
#pragma unroll
    for (int dkg = 0; dkg < 4; ++dkg)
      vb[dkg] = *(const bf16x8*)(vg + (size_t)(dkg * 16 + lr) * 8192 + kbase + lg * 8);

#pragma unroll
    for (int mi = 0; mi < 2; ++mi)
#pragma unroll
      for (int ni = 0; ni < 2; ++ni)
#pragma unroll
        for (int j = 0; j < 4; ++j) {
          const int row = mi * 16 + lg * 4 + j;
          const unsigned short gu = gg[(size_t)(q0 + row) * SS + kbase + ni * 16 + lr];
          const float e = exp2f(sc[mi][ni][j]);
          ssum[mi][j] += gu ? e : 0.0f;
          Pb[row * 40 + ni * 16 + lr] = f2bf(e * bf2f(gu));
        }

    __builtin_amdgcn_s_setprio(1);
#pragma unroll
    for (int mi = 0; mi < 2; ++mi) {
      const bf16x8 pa = *(const bf16x8*)(Pb + (mi * 16 + lr) * 40 + lg * 8);
#pragma unroll
      for (int dkg = 0; dkg < 4; ++dkg)
        acc[mi][dkg] = __builtin_amdgcn_mfma_f32_16x16x32_bf16(pa, vb[dkg], acc[mi][dkg], 0, 0, 0);
    }
    __builtin_amdgcn_s_setprio(0);
  }

#pragma unroll
  for (int mi = 0; mi < 2; ++mi)
#pragma unroll
    for (int j = 0; j < 4; ++j) {
      float s = ssum[mi][j];
      s += __shfl_xor(s, 1);
      s += __shfl_xor(s, 2);
      s += __shfl_xor(s, 4);
      s += __shfl_xor(s, 8);
      if (lr == 0) sumw[w * 32 + mi * 16 + lg * 4 + j] = s;
    }
  __syncthreads();

#pragma unroll
  for (int mi = 0; mi < 2; ++mi)
#pragma unroll
    for (int dkg = 0; dkg < 4; ++dkg)
#pragma unroll
      for (int j = 0; j < 4; ++j)
        pctx[(size_t)w * 2048 + (mi * 16 + lg * 4 + j) * 64 + dkg * 16 + lr] = acc[mi][dkg][j];
  __syncthreads();

  {
    const int row = tid >> 3;
    const int dk0 = (tid & 7) * 8;
    const float tot = sumw[row] + sumw[32 + row] + sumw[64 + row] + sumw[96 + row];
    const float inv = 1.0f / fmaxf(tot, 1e-30f);
    float vsum[8];
#pragma unroll
    for (int c = 0; c < 8; ++c) vsum[c] = 0.0f;
#pragma unroll
    for (int ww = 0; ww < 4; ++ww) {
      const float* p = pctx + (size_t)ww * 2048 + row * 64 + dk0;
      f32x4 a = *(const f32x4*)p;
      f32x4 bq = *(const f32x4*)(p + 4);
#pragma unroll
      for (int c = 0; c < 4; ++c) { vsum[c] += a[c]; vsum[4 + c] += bq[c]; }
    }
    ushort8 o;
#pragma unroll
    for (int c = 0; c < 8; ++c) o[c] = f2bf(vsum[c] * inv);
    *(ushort8*)(cg + (size_t)(q0 + row) * DD + dk0) = o;
  }
}

// ----------------------------------------------------------------------------
extern "C" void kernel_launch(void* const* d_in, const int* in_sizes, int n_in,
                              void* d_out, int out_size, void* d_ws, size_t ws_size,
                              hipStream_t stream) {
  (void)in_sizes; (void)n_in; (void)out_size; (void)ws_size;
  const float* x    = (const float*)d_in[0];
  const float* timep= (const float*)d_in[1];
  const float* Wq = (const float*)d_in[2];  const float* bq = (const float*)d_in[3];
  const float* Wk = (const float*)d_in[4];  const float* bk = (const float*)d_in[5];
  const float* Wt = (const float*)d_in[6];  const float* bt = (const float*)d_in[7];
  const float* Wv = (const float*)d_in[8];  const float* bv = (const float*)d_in[9];
  const float* Wo = (const float*)d_in[10]; const float* bo = (const float*)d_in[11];
  const float* W1 = (const float*)d_in[12]; const float* b1 = (const float*)d_in[13];
  const float* W2 = (const float*)d_in[14]; const float* b2 = (const float*)d_in[15];
  const float* ln1g = (const float*)d_in[16]; const float* ln1b = (const float*)d_in[17];
  const float* ln2g = (const float*)d_in[18]; const float* ln2b = (const float*)d_in[19];
  const float* ml   = (const float*)d_in[20];
  const int*   mask = (const int*)d_in[21];
  float* out = (float*)d_out;

  char* w = (char*)d_ws;
  auto alloc = [&](size_t sz) { char* p = w; w += (sz + 255) & ~(size_t)255; return p; };
  const int MT = BB * SS;  // 8192 rows

  unsigned short* WqvT = (unsigned short*)alloc((size_t)2048 * 1024 * 2);
  unsigned short* WkcT = (unsigned short*)alloc((size_t)1024 * 2048 * 2);
  unsigned short* WoT  = (unsigned short*)alloc((size_t)DD * DD * 2);
  unsigned short* W1T  = (unsigned short*)alloc((size_t)DD * DFFN * 2);
  unsigned short* W2T  = (unsigned short*)alloc((size_t)DFFN * DD * 2);
  float* qvb = (float*)alloc(2048 * 4);
  float* kcbias = (float*)alloc(1024 * 4);
  unsigned short* gateb = (unsigned short*)alloc((size_t)BB * SS * SS * 2);
  unsigned short* xt2 = (unsigned short*)alloc((size_t)MT * 2048 * 2);  // [xn | time]
  unsigned short* qbuf = (unsigned short*)alloc((size_t)MT * DD * 2);   // q (prescaled)
  unsigned short* vbuf = (unsigned short*)alloc((size_t)MT * DD * 2);   // v
  unsigned short* vTb = (unsigned short*)alloc((size_t)DD * MT * 2);    // v^T
  unsigned short* kcb = (unsigned short*)alloc((size_t)MT * DD * 2);    // k1+k2
  float*          x2  = (float*)alloc((size_t)MT * DD * 4);
  unsigned short* hb  = (unsigned short*)alloc((size_t)MT * DFFN * 2);
  unsigned short* ctx = xt2;
  unsigned short* xn2 = xt2;

  // merged prep
  prep_weights<<<dim3(13312), 256, 0, stream>>>(Wq, Wv, Wk, Wt, Wo, W1, W2,
                                                WqvT, WkcT, WoT, W1T, W2T);
  gate_build<<<dim3(BB * SS * SS / 8 / 256), 256, 0, stream>>>(mask, ml, gateb,
                                                               bq, bv, bk, bt, qvb, kcbias);
  ln_time<<<dim3(MT), 256, 0, stream>>>(x, ln1g, ln1b, timep, xt2);

  gemm8p<256, 3><<<dim3(256), 512, 0, stream>>>(xt2, 2048, WqvT, qvb, nullptr, (void*)qbuf, vbuf, MT, 2048, 1024);
  vtrans<<<dim3(16, 128), 256, 0, stream>>>(vbuf, vTb);
  gemm128<0><<<dim3(512), 256, 0, stream>>>(xt2, 2048, WkcT, kcbias, nullptr, (void*)kcb, MT, 1024, 2048);

  attn4<<<dim3(BB * HH * 16), 256, 0, stream>>>(qbuf, vTb, kcb, gateb, ctx);

  gemm128<1><<<dim3(512), 256, 0, stream>>>(ctx, 1024, WoT, bo, x, (void*)x2, MT, 1024, 1024);
  ln_kernel<<<dim3(MT), 256, 0, stream>>>(x2, ln2g, ln2b, xn2, 1024);
  gemm8p<256, 2><<<dim3(512), 512, 0, stream>>>(xn2, 1024, W1T, b1, nullptr, (void*)hb, nullptr, MT, 4096, 1024);
  gemm128<1><<<dim3(512), 256, 0, stream>>>(hb, 4096, W2T, b2, x2, (void*)out, MT, 1024, 4096);
}